// Round 1
// baseline (1473.042 us; speedup 1.0000x reference)
//
#include <hip/hip_runtime.h>

#define N_NODES 50000
#define N_EDGES 800000
#define D 128            // D_IN == D_OUT == 128
#define D4 32            // D / 4

// ---------------------------------------------------------------------------
// Kernel 1: h = x @ W   (fp32, vector ALU — no fp32 MFMA on CDNA4)
// Each block: 8 rows x 128 cols. Thread = (row_in_block = t>>5, col4 = t&31).
// W (64 KB) is read through L1/L2 — every block touches the same 64 KB.
// x row read as float4, broadcast across the 32 threads of the row-group.
// ---------------------------------------------------------------------------
__global__ __launch_bounds__(256) void gemm_xw(const float4* __restrict__ x4,
                                               const float4* __restrict__ w4,
                                               float4* __restrict__ h4) {
    const int t   = threadIdx.x;
    const int j4  = t & 31;                 // float4 column index 0..31
    const int row = blockIdx.x * 8 + (t >> 5);

    const float4* xrow = x4 + (size_t)row * D4;
    float4 acc = {0.f, 0.f, 0.f, 0.f};

    #pragma unroll
    for (int kk = 0; kk < D4; ++kk) {
        const float4 xv = xrow[kk];
        #pragma unroll
        for (int u = 0; u < 4; ++u) {
            const int k = kk * 4 + u;
            const float4 wv = w4[k * D4 + j4];
            const float xs = (u == 0) ? xv.x : (u == 1) ? xv.y : (u == 2) ? xv.z : xv.w;
            acc.x = fmaf(xs, wv.x, acc.x);
            acc.y = fmaf(xs, wv.y, acc.y);
            acc.z = fmaf(xs, wv.z, acc.z);
            acc.w = fmaf(xs, wv.w, acc.w);
        }
    }
    h4[(size_t)row * D4 + j4] = acc;
}

// ---------------------------------------------------------------------------
// Kernel 2: edge scatter. 32 threads per edge; each thread gathers one float4
// of h[col[e]], scales by vals[e], and atomically adds 4 floats into
// out[row[e]]. h (25.6 MB) and out (25.6 MB) are L2/L3-resident.
// ---------------------------------------------------------------------------
__global__ __launch_bounds__(256) void scatter_edges(const float* __restrict__ vals,
                                                     const int* __restrict__ rowi,
                                                     const int* __restrict__ coli,
                                                     const float4* __restrict__ h4,
                                                     float* __restrict__ out) {
    const int gt = blockIdx.x * 256 + threadIdx.x;
    const int e  = gt >> 5;
    const int d4 = gt & 31;
    if (e >= N_EDGES) return;

    const float v = vals[e];
    const int   c = coli[e];
    const int   r = rowi[e];

    const float4 hv = h4[(size_t)c * D4 + d4];
    float* o = out + (size_t)r * D + d4 * 4;
    atomicAdd(o + 0, v * hv.x);
    atomicAdd(o + 1, v * hv.y);
    atomicAdd(o + 2, v * hv.z);
    atomicAdd(o + 3, v * hv.w);
}

// ---------------------------------------------------------------------------
// Kernel 3: out = relu(out + bias), vectorized float4 in-place.
// ---------------------------------------------------------------------------
__global__ __launch_bounds__(256) void bias_relu(float4* __restrict__ out4,
                                                 const float4* __restrict__ bias4) {
    const int i = blockIdx.x * 256 + threadIdx.x;
    if (i >= N_NODES * D4) return;
    const float4 b = bias4[i & 31];
    float4 o = out4[i];
    o.x = fmaxf(o.x + b.x, 0.f);
    o.y = fmaxf(o.y + b.y, 0.f);
    o.z = fmaxf(o.z + b.z, 0.f);
    o.w = fmaxf(o.w + b.w, 0.f);
    out4[i] = o;
}

extern "C" void kernel_launch(void* const* d_in, const int* in_sizes, int n_in,
                              void* d_out, int out_size, void* d_ws, size_t ws_size,
                              hipStream_t stream) {
    const float* x      = (const float*)d_in[0];   // [N_NODES, D]
    const float* weight = (const float*)d_in[1];   // [D, D]
    const float* bias   = (const float*)d_in[2];   // [D]
    const float* vals   = (const float*)d_in[3];   // [N_EDGES]
    const int*   rowi   = (const int*)d_in[4];     // [N_EDGES]
    const int*   coli   = (const int*)d_in[5];     // [N_EDGES]
    float* out = (float*)d_out;                    // [N_NODES, D]

    float* h = (float*)d_ws;                       // [N_NODES, D] scratch, 25.6 MB

    // out must be zero before atomic accumulation (harness poisons once, and
    // we must be idempotent across replays).
    hipMemsetAsync(out, 0, (size_t)N_NODES * D * sizeof(float), stream);

    // h = x @ W
    gemm_xw<<<N_NODES / 8, 256, 0, stream>>>((const float4*)x, (const float4*)weight,
                                             (float4*)h);

    // out[row[e]] += vals[e] * h[col[e]]
    const int scatter_blocks = (N_EDGES * 32) / 256;   // 100000
    scatter_edges<<<scatter_blocks, 256, 0, stream>>>(vals, rowi, coli,
                                                      (const float4*)h, out);

    // out = relu(out + bias)
    bias_relu<<<(N_NODES * D4) / 256, 256, 0, stream>>>((float4*)out,
                                                        (const float4*)bias);
}

// Round 2
// 384.007 us; speedup vs baseline: 3.8360x; 3.8360x over previous
//
#include <hip/hip_runtime.h>

#define N_NODES 50000
#define N_EDGES 800000
#define D 128            // D_IN == D_OUT == 128
#define D4 32            // D / 4
#define D2 64            // D / 2

// ---------------------------------------------------------------------------
// Kernel 1: h = x @ W   (fp32, vector ALU — no fp32 MFMA on CDNA4)
// ---------------------------------------------------------------------------
__global__ __launch_bounds__(256) void gemm_xw(const float4* __restrict__ x4,
                                               const float4* __restrict__ w4,
                                               float4* __restrict__ h4) {
    const int t   = threadIdx.x;
    const int j4  = t & 31;                 // float4 column index 0..31
    const int row = blockIdx.x * 8 + (t >> 5);

    const float4* xrow = x4 + (size_t)row * D4;
    float4 acc = {0.f, 0.f, 0.f, 0.f};

    #pragma unroll
    for (int kk = 0; kk < D4; ++kk) {
        const float4 xv = xrow[kk];
        #pragma unroll
        for (int u = 0; u < 4; ++u) {
            const int k = kk * 4 + u;
            const float4 wv = w4[k * D4 + j4];
            const float xs = (u == 0) ? xv.x : (u == 1) ? xv.y : (u == 2) ? xv.z : xv.w;
            acc.x = fmaf(xs, wv.x, acc.x);
            acc.y = fmaf(xs, wv.y, acc.y);
            acc.z = fmaf(xs, wv.z, acc.z);
            acc.w = fmaf(xs, wv.w, acc.w);
        }
    }
    h4[(size_t)row * D4 + j4] = acc;
}

// ---------------------------------------------------------------------------
// CSR build step A: count edges per destination row (int atomics, cheap).
// ---------------------------------------------------------------------------
__global__ __launch_bounds__(256) void count_edges(const int* __restrict__ rowi,
                                                   int* __restrict__ cnt) {
    const int e = blockIdx.x * 256 + threadIdx.x;
    if (e < N_EDGES) atomicAdd(&cnt[rowi[e]], 1);
}

// ---------------------------------------------------------------------------
// CSR build step B: exclusive scan of 50000 counts. Single block, 1024 thr.
// Each thread owns a contiguous chunk of ceil(N/1024)=49 entries: local sum,
// Hillis-Steele block scan in LDS, then per-element exclusive prefixes.
// Writes starts[] and re-initializes cnt[] as the placement cursor.
// ---------------------------------------------------------------------------
#define SCAN_T 1024
#define CHUNK 49
__global__ __launch_bounds__(SCAN_T) void scan_counts(int* __restrict__ cnt,
                                                      int* __restrict__ starts) {
    __shared__ int part[SCAN_T];
    const int t  = threadIdx.x;
    const int lo = t * CHUNK;
    const int hi = min(lo + CHUNK, N_NODES);

    int local[CHUNK];
    int sum = 0;
    for (int i = lo; i < hi; ++i) {
        local[i - lo] = cnt[i];
        sum += local[i - lo];
    }
    part[t] = sum;
    __syncthreads();

    // inclusive Hillis-Steele scan over 1024 partials
    for (int off = 1; off < SCAN_T; off <<= 1) {
        int v = (t >= off) ? part[t - off] : 0;
        __syncthreads();
        part[t] += v;
        __syncthreads();
    }
    int run = (t == 0) ? 0 : part[t - 1];   // exclusive prefix of this chunk

    for (int i = lo; i < hi; ++i) {
        starts[i] = run;
        cnt[i]    = run;                    // cursor init for placement
        run += local[i - lo];
    }
    if (t == SCAN_T - 1) starts[N_NODES] = part[SCAN_T - 1];
}

// ---------------------------------------------------------------------------
// CSR build step C: place each edge's (col, val) into its row bucket.
// ---------------------------------------------------------------------------
__global__ __launch_bounds__(256) void place_edges(const int* __restrict__ rowi,
                                                   const int* __restrict__ coli,
                                                   const float* __restrict__ vals,
                                                   int* __restrict__ cursor,
                                                   int2* __restrict__ perm) {
    const int e = blockIdx.x * 256 + threadIdx.x;
    if (e >= N_EDGES) return;
    const int pos = atomicAdd(&cursor[rowi[e]], 1);
    perm[pos] = make_int2(coli[e], __float_as_int(vals[e]));
}

// ---------------------------------------------------------------------------
// Kernel 2: gather. One 64-lane wave per node; lane owns float2 of features.
// Edges prefetched 64-at-a-time coalesced, broadcast via __shfl. Accumulate
// in registers; fused bias + ReLU on the single output write. No atomics.
// ---------------------------------------------------------------------------
__global__ __launch_bounds__(256) void gather_nodes(const int* __restrict__ starts,
                                                    const int2* __restrict__ perm,
                                                    const float2* __restrict__ h2,
                                                    const float2* __restrict__ bias2,
                                                    float2* __restrict__ out2) {
    const int node = blockIdx.x * 4 + (threadIdx.x >> 6);
    const int lane = threadIdx.x & 63;
    if (node >= N_NODES) return;

    const int s = starts[node];
    const int e = starts[node + 1];

    float2 acc = {0.f, 0.f};
    for (int base = s; base < e; base += 64) {
        const int n = min(64, e - base);
        int2 ed = make_int2(0, 0);
        if (lane < n) ed = perm[base + lane];
        for (int j = 0; j < n; ++j) {
            const int   c = __shfl(ed.x, j);
            const float v = __int_as_float(__shfl(ed.y, j));
            const float2 hv = h2[(size_t)c * D2 + lane];
            acc.x = fmaf(v, hv.x, acc.x);
            acc.y = fmaf(v, hv.y, acc.y);
        }
    }
    const float2 b = bias2[lane];
    float2 o;
    o.x = fmaxf(acc.x + b.x, 0.f);
    o.y = fmaxf(acc.y + b.y, 0.f);
    out2[(size_t)node * D2 + lane] = o;
}

extern "C" void kernel_launch(void* const* d_in, const int* in_sizes, int n_in,
                              void* d_out, int out_size, void* d_ws, size_t ws_size,
                              hipStream_t stream) {
    const float* x      = (const float*)d_in[0];   // [N_NODES, D]
    const float* weight = (const float*)d_in[1];   // [D, D]
    const float* bias   = (const float*)d_in[2];   // [D]
    const float* vals   = (const float*)d_in[3];   // [N_EDGES]
    const int*   rowi   = (const int*)d_in[4];     // [N_EDGES]
    const int*   coli   = (const int*)d_in[5];     // [N_EDGES]
    float* out = (float*)d_out;                    // [N_NODES, D]

    // Workspace layout (all 16B-aligned):
    //   h      : N_NODES*D floats      = 25.6 MB
    //   starts : N_NODES+1 ints        ≈ 200 KB
    //   cnt    : N_NODES ints          = 200 KB   (counts, then cursor)
    //   perm   : N_EDGES int2          = 6.4 MB
    char* w = (char*)d_ws;
    float* h      = (float*)w;                     w += (size_t)N_NODES * D * sizeof(float);
    int*   starts = (int*)w;                       w += ((size_t)N_NODES + 16) * sizeof(int);
    int*   cnt    = (int*)w;                       w += ((size_t)N_NODES + 16) * sizeof(int);
    int2*  perm   = (int2*)w;

    // --- CSR build ---
    hipMemsetAsync(cnt, 0, (size_t)N_NODES * sizeof(int), stream);
    count_edges<<<N_EDGES / 256, 256, 0, stream>>>(rowi, cnt);
    scan_counts<<<1, SCAN_T, 0, stream>>>(cnt, starts);
    place_edges<<<N_EDGES / 256, 256, 0, stream>>>(rowi, coli, vals, cnt, perm);

    // --- h = x @ W ---
    gemm_xw<<<N_NODES / 8, 256, 0, stream>>>((const float4*)x, (const float4*)weight,
                                             (float4*)h);

    // --- out[i] = relu(sum_e vals[e]*h[col[e]] + bias), no atomics ---
    gather_nodes<<<(N_NODES + 3) / 4, 256, 0, stream>>>(starts, perm,
                                                        (const float2*)h,
                                                        (const float2*)bias,
                                                        (float2*)out);
}

// Round 3
// 278.846 us; speedup vs baseline: 5.2826x; 1.3771x over previous
//
#include <hip/hip_runtime.h>

#define N_NODES 50000
#define N_EDGES 800000
#define D 128            // D_IN == D_OUT == 128
#define D4 32            // D / 4
#define D2 64            // D / 2

#define SCAN_B 256                                  // elements per scan block
#define SCAN_NB ((N_NODES + SCAN_B - 1) / SCAN_B)   // 196

// ---------------------------------------------------------------------------
// Kernel 1: h = x @ W   (fp32, vector ALU — no fp32 MFMA on CDNA4)
// ---------------------------------------------------------------------------
__global__ __launch_bounds__(256) void gemm_xw(const float4* __restrict__ x4,
                                               const float4* __restrict__ w4,
                                               float4* __restrict__ h4) {
    const int t   = threadIdx.x;
    const int j4  = t & 31;                 // float4 column index 0..31
    const int row = blockIdx.x * 8 + (t >> 5);

    const float4* xrow = x4 + (size_t)row * D4;
    float4 acc = {0.f, 0.f, 0.f, 0.f};

    #pragma unroll
    for (int kk = 0; kk < D4; ++kk) {
        const float4 xv = xrow[kk];
        #pragma unroll
        for (int u = 0; u < 4; ++u) {
            const int k = kk * 4 + u;
            const float4 wv = w4[k * D4 + j4];
            const float xs = (u == 0) ? xv.x : (u == 1) ? xv.y : (u == 2) ? xv.z : xv.w;
            acc.x = fmaf(xs, wv.x, acc.x);
            acc.y = fmaf(xs, wv.y, acc.y);
            acc.z = fmaf(xs, wv.z, acc.z);
            acc.w = fmaf(xs, wv.w, acc.w);
        }
    }
    h4[(size_t)row * D4 + j4] = acc;
}

// ---------------------------------------------------------------------------
// CSR step A: count edges per destination row (int atomics, cheap).
// ---------------------------------------------------------------------------
__global__ __launch_bounds__(256) void count_edges(const int* __restrict__ rowi,
                                                   int* __restrict__ cnt) {
    const int e = blockIdx.x * 256 + threadIdx.x;
    if (e < N_EDGES) atomicAdd(&cnt[rowi[e]], 1);
}

// ---------------------------------------------------------------------------
// CSR step B1: per-block sums of cnt (196 blocks x 256).
// ---------------------------------------------------------------------------
__global__ __launch_bounds__(SCAN_B) void scan_phase1(const int* __restrict__ cnt,
                                                      int* __restrict__ partials) {
    __shared__ int red[SCAN_B / 64];
    const int t = threadIdx.x;
    const int i = blockIdx.x * SCAN_B + t;
    int v = (i < N_NODES) ? cnt[i] : 0;
    // wave reduce
    #pragma unroll
    for (int off = 32; off > 0; off >>= 1) v += __shfl_down(v, off);
    if ((t & 63) == 0) red[t >> 6] = v;
    __syncthreads();
    if (t == 0) partials[blockIdx.x] = red[0] + red[1] + red[2] + red[3];
}

// ---------------------------------------------------------------------------
// CSR step B2: exclusive scan of the 196 partials (single tiny block).
// ---------------------------------------------------------------------------
__global__ __launch_bounds__(SCAN_B) void scan_phase2(int* __restrict__ partials) {
    __shared__ int s[SCAN_B];
    const int t = threadIdx.x;
    int v = (t < SCAN_NB) ? partials[t] : 0;
    s[t] = v;
    __syncthreads();
    #pragma unroll
    for (int off = 1; off < SCAN_B; off <<= 1) {
        int u = (t >= off) ? s[t - off] : 0;
        __syncthreads();
        s[t] += u;
        __syncthreads();
    }
    if (t < SCAN_NB) partials[t] = (t == 0) ? 0 : s[t - 1];   // exclusive
}

// ---------------------------------------------------------------------------
// CSR step B3: per-block exclusive scan + block offset -> starts[] & cursor[].
// ---------------------------------------------------------------------------
__global__ __launch_bounds__(SCAN_B) void scan_phase3(int* __restrict__ cnt,
                                                      const int* __restrict__ partials,
                                                      int* __restrict__ starts) {
    __shared__ int s[SCAN_B];
    const int t = threadIdx.x;
    const int i = blockIdx.x * SCAN_B + t;
    int v = (i < N_NODES) ? cnt[i] : 0;
    s[t] = v;
    __syncthreads();
    #pragma unroll
    for (int off = 1; off < SCAN_B; off <<= 1) {
        int u = (t >= off) ? s[t - off] : 0;
        __syncthreads();
        s[t] += u;
        __syncthreads();
    }
    if (i < N_NODES) {
        const int excl = partials[blockIdx.x] + ((t == 0) ? 0 : s[t - 1]);
        starts[i] = excl;
        cnt[i]    = excl;                   // placement cursor
    }
    if (i == 0) starts[N_NODES] = N_EDGES;  // total is a compile-time constant
}

// ---------------------------------------------------------------------------
// CSR step C: place each edge's (col, val) into its row bucket.
// ---------------------------------------------------------------------------
__global__ __launch_bounds__(256) void place_edges(const int* __restrict__ rowi,
                                                   const int* __restrict__ coli,
                                                   const float* __restrict__ vals,
                                                   int* __restrict__ cursor,
                                                   int2* __restrict__ perm) {
    const int e = blockIdx.x * 256 + threadIdx.x;
    if (e >= N_EDGES) return;
    const int pos = atomicAdd(&cursor[rowi[e]], 1);
    perm[pos] = make_int2(coli[e], __float_as_int(vals[e]));
}

// ---------------------------------------------------------------------------
// Kernel 2: gather. One 64-lane wave per node; lane owns float2 of features.
// Edges fetched 64-at-a-time coalesced, broadcast via __shfl. Accumulate in
// registers; fused bias + ReLU on the single output write. No atomics.
// ---------------------------------------------------------------------------
__global__ __launch_bounds__(256) void gather_nodes(const int* __restrict__ starts,
                                                    const int2* __restrict__ perm,
                                                    const float2* __restrict__ h2,
                                                    const float2* __restrict__ bias2,
                                                    float2* __restrict__ out2) {
    const int node = blockIdx.x * 4 + (threadIdx.x >> 6);
    const int lane = threadIdx.x & 63;
    if (node >= N_NODES) return;

    const int s = starts[node];
    const int e = starts[node + 1];

    float2 acc = {0.f, 0.f};
    for (int base = s; base < e; base += 64) {
        const int n = min(64, e - base);
        int2 ed = make_int2(0, 0);
        if (lane < n) ed = perm[base + lane];
        for (int j = 0; j < n; ++j) {
            const int   c = __shfl(ed.x, j);
            const float v = __int_as_float(__shfl(ed.y, j));
            const float2 hv = h2[(size_t)c * D2 + lane];
            acc.x = fmaf(v, hv.x, acc.x);
            acc.y = fmaf(v, hv.y, acc.y);
        }
    }
    const float2 b = bias2[lane];
    float2 o;
    o.x = fmaxf(acc.x + b.x, 0.f);
    o.y = fmaxf(acc.y + b.y, 0.f);
    out2[(size_t)node * D2 + lane] = o;
}

extern "C" void kernel_launch(void* const* d_in, const int* in_sizes, int n_in,
                              void* d_out, int out_size, void* d_ws, size_t ws_size,
                              hipStream_t stream) {
    const float* x      = (const float*)d_in[0];   // [N_NODES, D]
    const float* weight = (const float*)d_in[1];   // [D, D]
    const float* bias   = (const float*)d_in[2];   // [D]
    const float* vals   = (const float*)d_in[3];   // [N_EDGES]
    const int*   rowi   = (const int*)d_in[4];     // [N_EDGES]
    const int*   coli   = (const int*)d_in[5];     // [N_EDGES]
    float* out = (float*)d_out;                    // [N_NODES, D]

    // Workspace layout (16B-aligned):
    //   h        : N_NODES*D floats   = 25.6 MB
    //   starts   : N_NODES+1 ints     ~ 200 KB
    //   cnt      : N_NODES ints       = 200 KB  (counts -> cursor)
    //   partials : SCAN_NB ints
    //   perm     : N_EDGES int2       = 6.4 MB
    char* w = (char*)d_ws;
    float* h        = (float*)w;  w += (size_t)N_NODES * D * sizeof(float);
    int*   starts   = (int*)w;    w += ((size_t)N_NODES + 16) * sizeof(int);
    int*   cnt      = (int*)w;    w += ((size_t)N_NODES + 16) * sizeof(int);
    int*   partials = (int*)w;    w += 256 * sizeof(int);
    int2*  perm     = (int2*)w;

    // --- CSR build ---
    hipMemsetAsync(cnt, 0, (size_t)N_NODES * sizeof(int), stream);
    count_edges<<<N_EDGES / 256, 256, 0, stream>>>(rowi, cnt);
    scan_phase1<<<SCAN_NB, SCAN_B, 0, stream>>>(cnt, partials);
    scan_phase2<<<1, SCAN_B, 0, stream>>>(partials);
    scan_phase3<<<SCAN_NB, SCAN_B, 0, stream>>>(cnt, partials, starts);
    place_edges<<<N_EDGES / 256, 256, 0, stream>>>(rowi, coli, vals, cnt, perm);

    // --- h = x @ W ---
    gemm_xw<<<N_NODES / 8, 256, 0, stream>>>((const float4*)x, (const float4*)weight,
                                             (float4*)h);

    // --- out[i] = relu(sum_e vals[e]*h[col[e]] + bias), no atomics ---
    gather_nodes<<<(N_NODES + 3) / 4, 256, 0, stream>>>(starts, perm,
                                                        (const float2*)h,
                                                        (const float2*)bias,
                                                        (float2*)out);
}

// Round 4
// 205.043 us; speedup vs baseline: 7.1841x; 1.3599x over previous
//
#include <hip/hip_runtime.h>

#define N_NODES 50000
#define N_EDGES 800000
#define D 128            // D_IN == D_OUT == 128
#define D4 32            // D / 4
#define D2 64            // D / 2

#define SCAN_B 256                                  // elements per scan block
#define SCAN_NB ((N_NODES + SCAN_B - 1) / SCAN_B)   // 196

#define GB_ROWS 128
#define GEMM_GRID_X ((N_NODES + GB_ROWS - 1) / GB_ROWS)   // 391
#define XS_STRIDE 33   // float4 stride: 132 floats -> row-groups land on disjoint banks

// ---------------------------------------------------------------------------
// Kernel 1: h = x @ W, fp32 register-tiled (no fp32 MFMA on CDNA4).
// Block: 128 rows x 64 cols, 256 threads; thread tile 8 rows x 4 cols.
// x tile in LDS (padded stride 33 f4: wave's 4 row-groups -> banks 0-3/4-7/
// 8-11/12-15, conflict-free). W read via L1 (32KB col-half, lane-broadcast).
// 128 FMAs per 12 loads per kk-step -> FMA-issue bound (~10.4 us floor).
// ---------------------------------------------------------------------------
__global__ __launch_bounds__(256) void gemm_xw(const float4* __restrict__ x4,
                                               const float4* __restrict__ w4,
                                               float4* __restrict__ h4) {
    __shared__ float4 xs[GB_ROWS * XS_STRIDE];
    const int t     = threadIdx.x;
    const int grow0 = blockIdx.x * GB_ROWS;

    // stage x tile: 128 rows x 32 float4 (guard rows >= N_NODES with zeros)
    #pragma unroll
    for (int i = 0; i < 16; ++i) {
        const int flat = t + i * 256;          // 0..4095
        const int row  = flat >> 5;
        const int c4   = flat & 31;
        float4 v = make_float4(0.f, 0.f, 0.f, 0.f);
        if (grow0 + row < N_NODES) v = x4[(size_t)(grow0 + row) * D4 + c4];
        xs[row * XS_STRIDE + c4] = v;
    }
    __syncthreads();

    const int tc = t & 15;                     // col group within half
    const int tr = t >> 4;                     // row group 0..15
    const int c4 = blockIdx.y * 16 + tc;       // global float4 col 0..31

    float4 acc[8];
    #pragma unroll
    for (int i = 0; i < 8; ++i) acc[i] = make_float4(0.f, 0.f, 0.f, 0.f);

    #pragma unroll 4
    for (int kk = 0; kk < 32; ++kk) {          // 4 k-values per iter
        float4 wv[4];
        #pragma unroll
        for (int u = 0; u < 4; ++u) wv[u] = w4[(size_t)(kk * 4 + u) * D4 + c4];
        #pragma unroll
        for (int i = 0; i < 8; ++i) {
            const float4 xv = xs[(tr + 16 * i) * XS_STRIDE + kk];
            acc[i].x = fmaf(xv.x, wv[0].x, acc[i].x);
            acc[i].y = fmaf(xv.x, wv[0].y, acc[i].y);
            acc[i].z = fmaf(xv.x, wv[0].z, acc[i].z);
            acc[i].w = fmaf(xv.x, wv[0].w, acc[i].w);
            acc[i].x = fmaf(xv.y, wv[1].x, acc[i].x);
            acc[i].y = fmaf(xv.y, wv[1].y, acc[i].y);
            acc[i].z = fmaf(xv.y, wv[1].z, acc[i].z);
            acc[i].w = fmaf(xv.y, wv[1].w, acc[i].w);
            acc[i].x = fmaf(xv.z, wv[2].x, acc[i].x);
            acc[i].y = fmaf(xv.z, wv[2].y, acc[i].y);
            acc[i].z = fmaf(xv.z, wv[2].z, acc[i].z);
            acc[i].w = fmaf(xv.z, wv[2].w, acc[i].w);
            acc[i].x = fmaf(xv.w, wv[3].x, acc[i].x);
            acc[i].y = fmaf(xv.w, wv[3].y, acc[i].y);
            acc[i].z = fmaf(xv.w, wv[3].z, acc[i].z);
            acc[i].w = fmaf(xv.w, wv[3].w, acc[i].w);
        }
    }

    #pragma unroll
    for (int i = 0; i < 8; ++i) {
        const int r = grow0 + tr + 16 * i;
        if (r < N_NODES) h4[(size_t)r * D4 + c4] = acc[i];
    }
}

// ---------------------------------------------------------------------------
// CSR step A: count edges per destination row (int atomics, cheap).
// ---------------------------------------------------------------------------
__global__ __launch_bounds__(256) void count_edges(const int* __restrict__ rowi,
                                                   int* __restrict__ cnt) {
    const int e = blockIdx.x * 256 + threadIdx.x;
    if (e < N_EDGES) atomicAdd(&cnt[rowi[e]], 1);
}

// ---------------------------------------------------------------------------
// CSR step B1: per-block sums of cnt (196 blocks x 256).
// ---------------------------------------------------------------------------
__global__ __launch_bounds__(SCAN_B) void scan_phase1(const int* __restrict__ cnt,
                                                      int* __restrict__ partials) {
    __shared__ int red[SCAN_B / 64];
    const int t = threadIdx.x;
    const int i = blockIdx.x * SCAN_B + t;
    int v = (i < N_NODES) ? cnt[i] : 0;
    #pragma unroll
    for (int off = 32; off > 0; off >>= 1) v += __shfl_down(v, off);
    if ((t & 63) == 0) red[t >> 6] = v;
    __syncthreads();
    if (t == 0) partials[blockIdx.x] = red[0] + red[1] + red[2] + red[3];
}

// ---------------------------------------------------------------------------
// CSR step B2: exclusive scan of the 196 partials (single tiny block).
// ---------------------------------------------------------------------------
__global__ __launch_bounds__(SCAN_B) void scan_phase2(int* __restrict__ partials) {
    __shared__ int s[SCAN_B];
    const int t = threadIdx.x;
    int v = (t < SCAN_NB) ? partials[t] : 0;
    s[t] = v;
    __syncthreads();
    #pragma unroll
    for (int off = 1; off < SCAN_B; off <<= 1) {
        int u = (t >= off) ? s[t - off] : 0;
        __syncthreads();
        s[t] += u;
        __syncthreads();
    }
    if (t < SCAN_NB) partials[t] = (t == 0) ? 0 : s[t - 1];   // exclusive
}

// ---------------------------------------------------------------------------
// CSR step B3: per-block exclusive scan + block offset -> starts[] & cursor[].
// ---------------------------------------------------------------------------
__global__ __launch_bounds__(SCAN_B) void scan_phase3(int* __restrict__ cnt,
                                                      const int* __restrict__ partials,
                                                      int* __restrict__ starts) {
    __shared__ int s[SCAN_B];
    const int t = threadIdx.x;
    const int i = blockIdx.x * SCAN_B + t;
    int v = (i < N_NODES) ? cnt[i] : 0;
    s[t] = v;
    __syncthreads();
    #pragma unroll
    for (int off = 1; off < SCAN_B; off <<= 1) {
        int u = (t >= off) ? s[t - off] : 0;
        __syncthreads();
        s[t] += u;
        __syncthreads();
    }
    if (i < N_NODES) {
        const int excl = partials[blockIdx.x] + ((t == 0) ? 0 : s[t - 1]);
        starts[i] = excl;
        cnt[i]    = excl;                   // placement cursor
    }
    if (i == 0) starts[N_NODES] = N_EDGES;  // total is a compile-time constant
}

// ---------------------------------------------------------------------------
// CSR step C: place each edge's (col, val) into its row bucket.
// ---------------------------------------------------------------------------
__global__ __launch_bounds__(256) void place_edges(const int* __restrict__ rowi,
                                                   const int* __restrict__ coli,
                                                   const float* __restrict__ vals,
                                                   int* __restrict__ cursor,
                                                   int2* __restrict__ perm) {
    const int e = blockIdx.x * 256 + threadIdx.x;
    if (e >= N_EDGES) return;
    const int pos = atomicAdd(&cursor[rowi[e]], 1);
    perm[pos] = make_int2(coli[e], __float_as_int(vals[e]));
}

// ---------------------------------------------------------------------------
// Kernel 2: gather. One 64-lane wave per node; lane owns float2 of features.
// Edges fetched 64-at-a-time coalesced, broadcast via __shfl. Accumulate in
// registers; fused bias + ReLU on the single output write. No atomics.
// ---------------------------------------------------------------------------
__global__ __launch_bounds__(256) void gather_nodes(const int* __restrict__ starts,
                                                    const int2* __restrict__ perm,
                                                    const float2* __restrict__ h2,
                                                    const float2* __restrict__ bias2,
                                                    float2* __restrict__ out2) {
    const int node = blockIdx.x * 4 + (threadIdx.x >> 6);
    const int lane = threadIdx.x & 63;
    if (node >= N_NODES) return;

    const int s = starts[node];
    const int e = starts[node + 1];

    float2 acc = {0.f, 0.f};
    for (int base = s; base < e; base += 64) {
        const int n = min(64, e - base);
        int2 ed = make_int2(0, 0);
        if (lane < n) ed = perm[base + lane];
        for (int j = 0; j < n; ++j) {
            const int   c = __shfl(ed.x, j);
            const float v = __int_as_float(__shfl(ed.y, j));
            const float2 hv = h2[(size_t)c * D2 + lane];
            acc.x = fmaf(v, hv.x, acc.x);
            acc.y = fmaf(v, hv.y, acc.y);
        }
    }
    const float2 b = bias2[lane];
    float2 o;
    o.x = fmaxf(acc.x + b.x, 0.f);
    o.y = fmaxf(acc.y + b.y, 0.f);
    out2[(size_t)node * D2 + lane] = o;
}

extern "C" void kernel_launch(void* const* d_in, const int* in_sizes, int n_in,
                              void* d_out, int out_size, void* d_ws, size_t ws_size,
                              hipStream_t stream) {
    const float* x      = (const float*)d_in[0];   // [N_NODES, D]
    const float* weight = (const float*)d_in[1];   // [D, D]
    const float* bias   = (const float*)d_in[2];   // [D]
    const float* vals   = (const float*)d_in[3];   // [N_EDGES]
    const int*   rowi   = (const int*)d_in[4];     // [N_EDGES]
    const int*   coli   = (const int*)d_in[5];     // [N_EDGES]
    float* out = (float*)d_out;                    // [N_NODES, D]

    // Workspace layout (16B-aligned):
    //   h        : N_NODES*D floats   = 25.6 MB
    //   starts   : N_NODES+1 ints     ~ 200 KB
    //   cnt      : N_NODES ints       = 200 KB  (counts -> cursor)
    //   partials : SCAN_NB ints
    //   perm     : N_EDGES int2       = 6.4 MB
    char* w = (char*)d_ws;
    float* h        = (float*)w;  w += (size_t)N_NODES * D * sizeof(float);
    int*   starts   = (int*)w;    w += ((size_t)N_NODES + 16) * sizeof(int);
    int*   cnt      = (int*)w;    w += ((size_t)N_NODES + 16) * sizeof(int);
    int*   partials = (int*)w;    w += 256 * sizeof(int);
    int2*  perm     = (int2*)w;

    // --- CSR build ---
    hipMemsetAsync(cnt, 0, (size_t)N_NODES * sizeof(int), stream);
    count_edges<<<N_EDGES / 256, 256, 0, stream>>>(rowi, cnt);
    scan_phase1<<<SCAN_NB, SCAN_B, 0, stream>>>(cnt, partials);
    scan_phase2<<<1, SCAN_B, 0, stream>>>(partials);
    scan_phase3<<<SCAN_NB, SCAN_B, 0, stream>>>(cnt, partials, starts);
    place_edges<<<N_EDGES / 256, 256, 0, stream>>>(rowi, coli, vals, cnt, perm);

    // --- h = x @ W (register-tiled fp32) ---
    gemm_xw<<<dim3(GEMM_GRID_X, 2), 256, 0, stream>>>((const float4*)x,
                                                      (const float4*)weight,
                                                      (float4*)h);

    // --- out[i] = relu(sum_e vals[e]*h[col[e]] + bias), no atomics ---
    gather_nodes<<<(N_NODES + 3) / 4, 256, 0, stream>>>(starts, perm,
                                                        (const float2*)h,
                                                        (const float2*)bias,
                                                        (float2*)out);
}

// Round 5
// 176.610 us; speedup vs baseline: 8.3406x; 1.1610x over previous
//
#include <hip/hip_runtime.h>

#define N_NODES 50000
#define N_EDGES 800000
#define D 128            // D_IN == D_OUT == 128
#define D4 32            // D / 4
#define D2 64            // D / 2

#define SCAN_B 256                                  // elements per scan block
#define SCAN_NB ((N_NODES + SCAN_B - 1) / SCAN_B)   // 196

#define GB_ROWS 128
#define GEMM_GRID_X ((N_NODES + GB_ROWS - 1) / GB_ROWS)   // 391

// ---- bf16 pack/unpack helpers (RTNE pack; unpack is shift/mask) ----------
__device__ __forceinline__ unsigned bf16_1(float a) {
    unsigned u = __float_as_uint(a);
    return (u + 0x7fffu + ((u >> 16) & 1u)) >> 16;
}
__device__ __forceinline__ unsigned pack_bf16(float a, float b) {
    return bf16_1(a) | (bf16_1(b) << 16);
}
__device__ __forceinline__ float ubf_lo(unsigned u) {
    return __uint_as_float(u << 16);
}
__device__ __forceinline__ float ubf_hi(unsigned u) {
    return __uint_as_float(u & 0xffff0000u);
}

// ---------------------------------------------------------------------------
// Kernel 1: h = x @ W, fp32 register-tiled on the VALU (no fp32 MFMA on CDNA4).
// Block: 512 threads = 128 rows x 128 cols; thread tile 8 rows x 4 cols.
// x tile staged in LDS as packed bf16 (32 KB -> 2+ blocks/CU). All LDS reads
// are half-wave broadcasts (same address across 32 lanes) -> conflict-free.
// W read through L2 (32 distinct float4 per wave per k, coalesced).
// h written as packed bf16 (uint2 = 4 features) for the gather stage.
// ---------------------------------------------------------------------------
__global__ __launch_bounds__(512) void gemm_xw(const float4* __restrict__ x4,
                                               const float4* __restrict__ w4,
                                               uint2* __restrict__ hb2) {
    __shared__ uint2 xs[GB_ROWS * 32];              // 128 rows x 128 bf16 = 32 KB
    const int t     = threadIdx.x;
    const int grow0 = blockIdx.x * GB_ROWS;

    // stage x tile as bf16 (zero-fill guard rows)
    #pragma unroll
    for (int i = 0; i < 8; ++i) {
        const int flat = t + i * 512;               // 0..4095
        const int row  = flat >> 5;
        const int c4   = flat & 31;
        float4 v = make_float4(0.f, 0.f, 0.f, 0.f);
        if (grow0 + row < N_NODES) v = x4[(size_t)(grow0 + row) * D4 + c4];
        xs[row * 32 + c4] = make_uint2(pack_bf16(v.x, v.y), pack_bf16(v.z, v.w));
    }
    __syncthreads();

    const int tc = t & 31;                          // float4 column group 0..31
    const int tr = t >> 5;                          // row group 0..15

    float4 acc[8];
    #pragma unroll
    for (int i = 0; i < 8; ++i) acc[i] = make_float4(0.f, 0.f, 0.f, 0.f);

    #pragma unroll 2
    for (int kk = 0; kk < 32; ++kk) {               // 4 k-values per iter
        float4 wv[4];
        #pragma unroll
        for (int u = 0; u < 4; ++u) wv[u] = w4[(size_t)(kk * 4 + u) * D4 + tc];
        #pragma unroll
        for (int i = 0; i < 8; ++i) {
            const uint2 xu = xs[(tr + 16 * i) * 32 + kk];
            const float x0 = ubf_lo(xu.x), x1 = ubf_hi(xu.x);
            const float x2 = ubf_lo(xu.y), x3 = ubf_hi(xu.y);
            acc[i].x = fmaf(x0, wv[0].x, acc[i].x);
            acc[i].y = fmaf(x0, wv[0].y, acc[i].y);
            acc[i].z = fmaf(x0, wv[0].z, acc[i].z);
            acc[i].w = fmaf(x0, wv[0].w, acc[i].w);
            acc[i].x = fmaf(x1, wv[1].x, acc[i].x);
            acc[i].y = fmaf(x1, wv[1].y, acc[i].y);
            acc[i].z = fmaf(x1, wv[1].z, acc[i].z);
            acc[i].w = fmaf(x1, wv[1].w, acc[i].w);
            acc[i].x = fmaf(x2, wv[2].x, acc[i].x);
            acc[i].y = fmaf(x2, wv[2].y, acc[i].y);
            acc[i].z = fmaf(x2, wv[2].z, acc[i].z);
            acc[i].w = fmaf(x2, wv[2].w, acc[i].w);
            acc[i].x = fmaf(x3, wv[3].x, acc[i].x);
            acc[i].y = fmaf(x3, wv[3].y, acc[i].y);
            acc[i].z = fmaf(x3, wv[3].z, acc[i].z);
            acc[i].w = fmaf(x3, wv[3].w, acc[i].w);
        }
    }

    #pragma unroll
    for (int i = 0; i < 8; ++i) {
        const int r = grow0 + tr + 16 * i;
        if (r < N_NODES)
            hb2[(size_t)r * 32 + tc] = make_uint2(pack_bf16(acc[i].x, acc[i].y),
                                                  pack_bf16(acc[i].z, acc[i].w));
    }
}

// ---------------------------------------------------------------------------
// CSR step A: count edges per destination row (int atomics, cheap).
// ---------------------------------------------------------------------------
__global__ __launch_bounds__(256) void count_edges(const int* __restrict__ rowi,
                                                   int* __restrict__ cnt) {
    const int e = blockIdx.x * 256 + threadIdx.x;
    if (e < N_EDGES) atomicAdd(&cnt[rowi[e]], 1);
}

// ---------------------------------------------------------------------------
// CSR step B1: per-block sums of cnt (196 blocks x 256).
// ---------------------------------------------------------------------------
__global__ __launch_bounds__(SCAN_B) void scan_phase1(const int* __restrict__ cnt,
                                                      int* __restrict__ partials) {
    __shared__ int red[SCAN_B / 64];
    const int t = threadIdx.x;
    const int i = blockIdx.x * SCAN_B + t;
    int v = (i < N_NODES) ? cnt[i] : 0;
    #pragma unroll
    for (int off = 32; off > 0; off >>= 1) v += __shfl_down(v, off);
    if ((t & 63) == 0) red[t >> 6] = v;
    __syncthreads();
    if (t == 0) partials[blockIdx.x] = red[0] + red[1] + red[2] + red[3];
}

// ---------------------------------------------------------------------------
// CSR step B2: exclusive scan of the 196 partials (single tiny block).
// ---------------------------------------------------------------------------
__global__ __launch_bounds__(SCAN_B) void scan_phase2(int* __restrict__ partials) {
    __shared__ int s[SCAN_B];
    const int t = threadIdx.x;
    int v = (t < SCAN_NB) ? partials[t] : 0;
    s[t] = v;
    __syncthreads();
    #pragma unroll
    for (int off = 1; off < SCAN_B; off <<= 1) {
        int u = (t >= off) ? s[t - off] : 0;
        __syncthreads();
        s[t] += u;
        __syncthreads();
    }
    if (t < SCAN_NB) partials[t] = (t == 0) ? 0 : s[t - 1];   // exclusive
}

// ---------------------------------------------------------------------------
// CSR step B3: per-block exclusive scan + block offset -> starts[] & cursor[].
// ---------------------------------------------------------------------------
__global__ __launch_bounds__(SCAN_B) void scan_phase3(int* __restrict__ cnt,
                                                      const int* __restrict__ partials,
                                                      int* __restrict__ starts) {
    __shared__ int s[SCAN_B];
    const int t = threadIdx.x;
    const int i = blockIdx.x * SCAN_B + t;
    int v = (i < N_NODES) ? cnt[i] : 0;
    s[t] = v;
    __syncthreads();
    #pragma unroll
    for (int off = 1; off < SCAN_B; off <<= 1) {
        int u = (t >= off) ? s[t - off] : 0;
        __syncthreads();
        s[t] += u;
        __syncthreads();
    }
    if (i < N_NODES) {
        const int excl = partials[blockIdx.x] + ((t == 0) ? 0 : s[t - 1]);
        starts[i] = excl;
        cnt[i]    = excl;                   // placement cursor
    }
    if (i == 0) starts[N_NODES] = N_EDGES;  // total is a compile-time constant
}

// ---------------------------------------------------------------------------
// CSR step C: place each edge's (col, val) into its row bucket.
// ---------------------------------------------------------------------------
__global__ __launch_bounds__(256) void place_edges(const int* __restrict__ rowi,
                                                   const int* __restrict__ coli,
                                                   const float* __restrict__ vals,
                                                   int* __restrict__ cursor,
                                                   int2* __restrict__ perm) {
    const int e = blockIdx.x * 256 + threadIdx.x;
    if (e >= N_EDGES) return;
    const int pos = atomicAdd(&cursor[rowi[e]], 1);
    perm[pos] = make_int2(coli[e], __float_as_int(vals[e]));
}

// ---------------------------------------------------------------------------
// Kernel 2: gather. One 64-lane wave per node; lane owns 2 features (one
// packed-bf16 uint of h). Edge records are read at wave-uniform addresses
// (scalar path via readfirstlane), 4 edges unrolled -> 4 gathers in flight.
// Fused bias + ReLU on the single fp32 output write. No atomics.
// ---------------------------------------------------------------------------
__global__ __launch_bounds__(256) void gather_nodes(const int* __restrict__ starts,
                                                    const int2* __restrict__ perm,
                                                    const unsigned* __restrict__ hb,
                                                    const float2* __restrict__ bias2,
                                                    float2* __restrict__ out2) {
    const int node = blockIdx.x * 4 + (threadIdx.x >> 6);
    const int lane = threadIdx.x & 63;
    if (node >= N_NODES) return;

    const int s = __builtin_amdgcn_readfirstlane(starts[node]);
    const int e = __builtin_amdgcn_readfirstlane(starts[node + 1]);

    float2 acc = {0.f, 0.f};
    for (int j0 = s; j0 < e; j0 += 4) {
        unsigned hv[4];
        float    vv[4];
        #pragma unroll
        for (int q = 0; q < 4; ++q) {
            const int jq = j0 + q;
            const int jj = (jq < e) ? jq : (e - 1);         // clamp; masked by vv=0
            const int2 ed = perm[jj];                        // wave-uniform address
            const int   c = __builtin_amdgcn_readfirstlane(ed.x);
            const float v = __int_as_float(__builtin_amdgcn_readfirstlane(ed.y));
            vv[q] = (jq < e) ? v : 0.f;
            hv[q] = hb[(size_t)c * 64 + lane];               // 256B/edge, coalesced
        }
        #pragma unroll
        for (int q = 0; q < 4; ++q) {
            acc.x = fmaf(vv[q], ubf_lo(hv[q]), acc.x);
            acc.y = fmaf(vv[q], ubf_hi(hv[q]), acc.y);
        }
    }
    const float2 b = bias2[lane];
    out2[(size_t)node * D2 + lane] =
        make_float2(fmaxf(acc.x + b.x, 0.f), fmaxf(acc.y + b.y, 0.f));
}

extern "C" void kernel_launch(void* const* d_in, const int* in_sizes, int n_in,
                              void* d_out, int out_size, void* d_ws, size_t ws_size,
                              hipStream_t stream) {
    const float* x      = (const float*)d_in[0];   // [N_NODES, D]
    const float* weight = (const float*)d_in[1];   // [D, D]
    const float* bias   = (const float*)d_in[2];   // [D]
    const float* vals   = (const float*)d_in[3];   // [N_EDGES]
    const int*   rowi   = (const int*)d_in[4];     // [N_EDGES]
    const int*   coli   = (const int*)d_in[5];     // [N_EDGES]
    float* out = (float*)d_out;                    // [N_NODES, D]

    // Workspace layout (16B-aligned):
    //   hb       : N_NODES*64 uints (packed bf16 h) = 12.8 MB
    //   starts   : N_NODES+1 ints   ~ 200 KB
    //   cnt      : N_NODES ints     = 200 KB  (counts -> cursor)
    //   partials : 256 ints
    //   perm     : N_EDGES int2     = 6.4 MB
    char* w = (char*)d_ws;
    unsigned* hb     = (unsigned*)w;  w += (size_t)N_NODES * 64 * sizeof(unsigned);
    int*   starts    = (int*)w;       w += ((size_t)N_NODES + 16) * sizeof(int);
    int*   cnt       = (int*)w;       w += ((size_t)N_NODES + 16) * sizeof(int);
    int*   partials  = (int*)w;       w += 256 * sizeof(int);
    int2*  perm      = (int2*)w;

    // --- CSR build ---
    hipMemsetAsync(cnt, 0, (size_t)N_NODES * sizeof(int), stream);
    count_edges<<<N_EDGES / 256, 256, 0, stream>>>(rowi, cnt);
    scan_phase1<<<SCAN_NB, SCAN_B, 0, stream>>>(cnt, partials);
    scan_phase2<<<1, SCAN_B, 0, stream>>>(partials);
    scan_phase3<<<SCAN_NB, SCAN_B, 0, stream>>>(cnt, partials, starts);
    place_edges<<<N_EDGES / 256, 256, 0, stream>>>(rowi, coli, vals, cnt, perm);

    // --- h = x @ W (register-tiled fp32, bf16 output) ---
    gemm_xw<<<GEMM_GRID_X, 512, 0, stream>>>((const float4*)x,
                                             (const float4*)weight,
                                             (uint2*)hb);

    // --- out[i] = relu(sum_e vals[e]*h[col[e]] + bias), no atomics ---
    gather_nodes<<<(N_NODES + 3) / 4, 256, 0, stream>>>(starts, perm, hb,
                                                        (const float2*)bias,
                                                        (float2*)out);
}

// Round 6
// 132.022 us; speedup vs baseline: 11.1575x; 1.3377x over previous
//
#include <hip/hip_runtime.h>

#define N_NODES 50000
#define N_EDGES 800000
#define D 128            // D_IN == D_OUT == 128
#define D4 32            // D / 4
#define D2 64            // D / 2

#define SCAN_B 256                                  // elements per scan block
#define SCAN_NB ((N_NODES + SCAN_B - 1) / SCAN_B)   // 196

#define GB_ROWS 128
#define GEMM_GRID_X ((N_NODES + GB_ROWS - 1) / GB_ROWS)   // 391

// ---- bf16 pack/unpack helpers (RTNE pack; unpack is shift/mask) ----------
__device__ __forceinline__ unsigned bf16_1(float a) {
    unsigned u = __float_as_uint(a);
    return (u + 0x7fffu + ((u >> 16) & 1u)) >> 16;
}
__device__ __forceinline__ unsigned pack_bf16(float a, float b) {
    return bf16_1(a) | (bf16_1(b) << 16);
}
__device__ __forceinline__ float ubf_lo(unsigned u) {
    return __uint_as_float(u << 16);
}
__device__ __forceinline__ float ubf_hi(unsigned u) {
    return __uint_as_float(u & 0xffff0000u);
}

// ---------------------------------------------------------------------------
// Kernel 1: h = x @ W, fp32 register-tiled on the VALU (no fp32 MFMA on CDNA4).
// Block: 512 threads = 128 rows x 128 cols; thread tile 8 rows x 4 cols.
// x tile staged in LDS as packed bf16 (32 KB). LDS reads are half-wave
// broadcasts (conflict-free). h written as packed bf16 for the gather stage.
// ---------------------------------------------------------------------------
__global__ __launch_bounds__(512) void gemm_xw(const float4* __restrict__ x4,
                                               const float4* __restrict__ w4,
                                               uint2* __restrict__ hb2) {
    __shared__ uint2 xs[GB_ROWS * 32];              // 128 rows x 128 bf16 = 32 KB
    const int t     = threadIdx.x;
    const int grow0 = blockIdx.x * GB_ROWS;

    #pragma unroll
    for (int i = 0; i < 8; ++i) {
        const int flat = t + i * 512;               // 0..4095
        const int row  = flat >> 5;
        const int c4   = flat & 31;
        float4 v = make_float4(0.f, 0.f, 0.f, 0.f);
        if (grow0 + row < N_NODES) v = x4[(size_t)(grow0 + row) * D4 + c4];
        xs[row * 32 + c4] = make_uint2(pack_bf16(v.x, v.y), pack_bf16(v.z, v.w));
    }
    __syncthreads();

    const int tc = t & 31;                          // float4 column group 0..31
    const int tr = t >> 5;                          // row group 0..15

    float4 acc[8];
    #pragma unroll
    for (int i = 0; i < 8; ++i) acc[i] = make_float4(0.f, 0.f, 0.f, 0.f);

    #pragma unroll 2
    for (int kk = 0; kk < 32; ++kk) {               // 4 k-values per iter
        float4 wv[4];
        #pragma unroll
        for (int u = 0; u < 4; ++u) wv[u] = w4[(size_t)(kk * 4 + u) * D4 + tc];
        #pragma unroll
        for (int i = 0; i < 8; ++i) {
            const uint2 xu = xs[(tr + 16 * i) * 32 + kk];
            const float x0 = ubf_lo(xu.x), x1 = ubf_hi(xu.x);
            const float x2 = ubf_lo(xu.y), x3 = ubf_hi(xu.y);
            acc[i].x = fmaf(x0, wv[0].x, acc[i].x);
            acc[i].y = fmaf(x0, wv[0].y, acc[i].y);
            acc[i].z = fmaf(x0, wv[0].z, acc[i].z);
            acc[i].w = fmaf(x0, wv[0].w, acc[i].w);
            acc[i].x = fmaf(x1, wv[1].x, acc[i].x);
            acc[i].y = fmaf(x1, wv[1].y, acc[i].y);
            acc[i].z = fmaf(x1, wv[1].z, acc[i].z);
            acc[i].w = fmaf(x1, wv[1].w, acc[i].w);
            acc[i].x = fmaf(x2, wv[2].x, acc[i].x);
            acc[i].y = fmaf(x2, wv[2].y, acc[i].y);
            acc[i].z = fmaf(x2, wv[2].z, acc[i].z);
            acc[i].w = fmaf(x2, wv[2].w, acc[i].w);
            acc[i].x = fmaf(x3, wv[3].x, acc[i].x);
            acc[i].y = fmaf(x3, wv[3].y, acc[i].y);
            acc[i].z = fmaf(x3, wv[3].z, acc[i].z);
            acc[i].w = fmaf(x3, wv[3].w, acc[i].w);
        }
    }

    #pragma unroll
    for (int i = 0; i < 8; ++i) {
        const int r = grow0 + tr + 16 * i;
        if (r < N_NODES)
            hb2[(size_t)r * 32 + tc] = make_uint2(pack_bf16(acc[i].x, acc[i].y),
                                                  pack_bf16(acc[i].z, acc[i].w));
    }
}

// ---------------------------------------------------------------------------
// CSR step A: count edges per row AND hand each edge its within-row ticket.
// pos[] write is sequential/coalesced (3.2 MB).
// ---------------------------------------------------------------------------
__global__ __launch_bounds__(256) void count_tickets(const int* __restrict__ rowi,
                                                     int* __restrict__ cnt,
                                                     int* __restrict__ pos) {
    const int e = blockIdx.x * 256 + threadIdx.x;
    if (e < N_EDGES) pos[e] = atomicAdd(&cnt[rowi[e]], 1);
}

// ---------------------------------------------------------------------------
// CSR step B1: per-block sums of cnt (196 blocks x 256).
// ---------------------------------------------------------------------------
__global__ __launch_bounds__(SCAN_B) void scan_phase1(const int* __restrict__ cnt,
                                                      int* __restrict__ partials) {
    __shared__ int red[SCAN_B / 64];
    const int t = threadIdx.x;
    const int i = blockIdx.x * SCAN_B + t;
    int v = (i < N_NODES) ? cnt[i] : 0;
    #pragma unroll
    for (int off = 32; off > 0; off >>= 1) v += __shfl_down(v, off);
    if ((t & 63) == 0) red[t >> 6] = v;
    __syncthreads();
    if (t == 0) partials[blockIdx.x] = red[0] + red[1] + red[2] + red[3];
}

// ---------------------------------------------------------------------------
// CSR step B2: exclusive scan of the 196 partials (single tiny block).
// ---------------------------------------------------------------------------
__global__ __launch_bounds__(SCAN_B) void scan_phase2(int* __restrict__ partials) {
    __shared__ int s[SCAN_B];
    const int t = threadIdx.x;
    int v = (t < SCAN_NB) ? partials[t] : 0;
    s[t] = v;
    __syncthreads();
    #pragma unroll
    for (int off = 1; off < SCAN_B; off <<= 1) {
        int u = (t >= off) ? s[t - off] : 0;
        __syncthreads();
        s[t] += u;
        __syncthreads();
    }
    if (t < SCAN_NB) partials[t] = (t == 0) ? 0 : s[t - 1];   // exclusive
}

// ---------------------------------------------------------------------------
// CSR step B3: per-block exclusive scan + block offset -> starts[].
// ---------------------------------------------------------------------------
__global__ __launch_bounds__(SCAN_B) void scan_phase3(const int* __restrict__ cnt,
                                                      const int* __restrict__ partials,
                                                      int* __restrict__ starts) {
    __shared__ int s[SCAN_B];
    const int t = threadIdx.x;
    const int i = blockIdx.x * SCAN_B + t;
    int v = (i < N_NODES) ? cnt[i] : 0;
    s[t] = v;
    __syncthreads();
    #pragma unroll
    for (int off = 1; off < SCAN_B; off <<= 1) {
        int u = (t >= off) ? s[t - off] : 0;
        __syncthreads();
        s[t] += u;
        __syncthreads();
    }
    if (i < N_NODES)
        starts[i] = partials[blockIdx.x] + ((t == 0) ? 0 : s[t - 1]);
    if (i == 0) starts[N_NODES] = N_EDGES;  // total is a compile-time constant
}

// ---------------------------------------------------------------------------
// CSR step C: place each edge's packed (col:16 | bf16(val):16) word at
// starts[row] + ticket. No atomics; 4 B random write per edge.
// ---------------------------------------------------------------------------
__global__ __launch_bounds__(256) void place_edges(const int* __restrict__ rowi,
                                                   const int* __restrict__ coli,
                                                   const float* __restrict__ vals,
                                                   const int* __restrict__ pos,
                                                   const int* __restrict__ starts,
                                                   unsigned* __restrict__ perm) {
    const int e = blockIdx.x * 256 + threadIdx.x;
    if (e >= N_EDGES) return;
    const int p = starts[rowi[e]] + pos[e];
    perm[p] = ((unsigned)coli[e] << 16) | bf16_1(vals[e]);
}

// ---------------------------------------------------------------------------
// Kernel 2: gather. One 64-lane wave per node; lane owns 2 features (one
// packed-bf16 uint of h). 8 edges unrolled -> 8 row-gathers in flight; tail
// loads clamp to the last real edge (L1 hit) with zeroed weight.
// Fused bias + ReLU on the single fp32 output write. No atomics.
// ---------------------------------------------------------------------------
__global__ __launch_bounds__(256) void gather_nodes(const int* __restrict__ starts,
                                                    const unsigned* __restrict__ perm,
                                                    const unsigned* __restrict__ hb,
                                                    const float2* __restrict__ bias2,
                                                    float2* __restrict__ out2) {
    const int node = blockIdx.x * 4 + (threadIdx.x >> 6);
    const int lane = threadIdx.x & 63;
    if (node >= N_NODES) return;

    const int s = __builtin_amdgcn_readfirstlane(starts[node]);
    const int e = __builtin_amdgcn_readfirstlane(starts[node + 1]);

    float2 acc = {0.f, 0.f};
    for (int j0 = s; j0 < e; j0 += 8) {
        unsigned hv[8];
        float    vv[8];
        #pragma unroll
        for (int q = 0; q < 8; ++q) {
            const int jq = j0 + q;
            const int jj = (jq < e) ? jq : (e - 1);          // clamp -> L1 hit
            const unsigned ed = __builtin_amdgcn_readfirstlane(perm[jj]);
            const int c = (int)(ed >> 16);
            vv[q] = (jq < e) ? __uint_as_float((ed & 0xffffu) << 16) : 0.f;
            hv[q] = hb[(size_t)c * 64 + lane];               // 256B/edge, coalesced
        }
        #pragma unroll
        for (int q = 0; q < 8; ++q) {
            acc.x = fmaf(vv[q], ubf_lo(hv[q]), acc.x);
            acc.y = fmaf(vv[q], ubf_hi(hv[q]), acc.y);
        }
    }
    const float2 b = bias2[lane];
    out2[(size_t)node * D2 + lane] =
        make_float2(fmaxf(acc.x + b.x, 0.f), fmaxf(acc.y + b.y, 0.f));
}

extern "C" void kernel_launch(void* const* d_in, const int* in_sizes, int n_in,
                              void* d_out, int out_size, void* d_ws, size_t ws_size,
                              hipStream_t stream) {
    const float* x      = (const float*)d_in[0];   // [N_NODES, D]
    const float* weight = (const float*)d_in[1];   // [D, D]
    const float* bias   = (const float*)d_in[2];   // [D]
    const float* vals   = (const float*)d_in[3];   // [N_EDGES]
    const int*   rowi   = (const int*)d_in[4];     // [N_EDGES]
    const int*   coli   = (const int*)d_in[5];     // [N_EDGES]
    float* out = (float*)d_out;                    // [N_NODES, D]

    // Workspace layout (16B-aligned):
    //   hb       : N_NODES*64 uints (packed bf16 h) = 12.8 MB
    //   starts   : N_NODES+1 ints   ~ 200 KB
    //   cnt      : N_NODES ints     = 200 KB
    //   pos      : N_EDGES ints     = 3.2 MB  (tickets)
    //   partials : 256 ints
    //   perm     : N_EDGES uints    = 3.2 MB  (packed col|bf16 val)
    char* w = (char*)d_ws;
    unsigned* hb     = (unsigned*)w;  w += (size_t)N_NODES * 64 * sizeof(unsigned);
    int*   starts    = (int*)w;       w += ((size_t)N_NODES + 16) * sizeof(int);
    int*   cnt       = (int*)w;       w += ((size_t)N_NODES + 16) * sizeof(int);
    int*   pos       = (int*)w;       w += (size_t)N_EDGES * sizeof(int);
    int*   partials  = (int*)w;       w += 256 * sizeof(int);
    unsigned* perm   = (unsigned*)w;

    // --- CSR build (ticketed, single atomic pass) ---
    hipMemsetAsync(cnt, 0, (size_t)N_NODES * sizeof(int), stream);
    count_tickets<<<N_EDGES / 256, 256, 0, stream>>>(rowi, cnt, pos);
    scan_phase1<<<SCAN_NB, SCAN_B, 0, stream>>>(cnt, partials);
    scan_phase2<<<1, SCAN_B, 0, stream>>>(partials);
    scan_phase3<<<SCAN_NB, SCAN_B, 0, stream>>>(cnt, partials, starts);
    place_edges<<<N_EDGES / 256, 256, 0, stream>>>(rowi, coli, vals, pos, starts, perm);

    // --- h = x @ W (register-tiled fp32, bf16 output) ---
    gemm_xw<<<GEMM_GRID_X, 512, 0, stream>>>((const float4*)x,
                                             (const float4*)weight,
                                             (uint2*)hb);

    // --- out[i] = relu(sum_e vals[e]*h[col[e]] + bias), no atomics ---
    gather_nodes<<<(N_NODES + 3) / 4, 256, 0, stream>>>(starts, perm, hb,
                                                        (const float2*)bias,
                                                        (float2*)out);
}

// Round 7
// 120.358 us; speedup vs baseline: 12.2388x; 1.0969x over previous
//
#include <hip/hip_runtime.h>

#define N_NODES 50000
#define N_EDGES 800000
#define D 128            // D_IN == D_OUT == 128
#define D4 32            // D / 4
#define D2 64            // D / 2

#define SCAN_B 256                                  // elements per scan block
#define SCAN_NB ((N_NODES + SCAN_B - 1) / SCAN_B)   // 196

typedef __attribute__((ext_vector_type(8))) short bf16x8;   // 8 bf16 in 4 VGPRs
typedef __attribute__((ext_vector_type(4))) float f32x4;

// ---- bf16 pack/unpack helpers (RTNE pack; unpack is shift/mask) ----------
__device__ __forceinline__ unsigned bf16_1(float a) {
    unsigned u = __float_as_uint(a);
    return (u + 0x7fffu + ((u >> 16) & 1u)) >> 16;
}
__device__ __forceinline__ unsigned pack_bf16(float a, float b) {
    return bf16_1(a) | (bf16_1(b) << 16);
}
__device__ __forceinline__ float ubf_lo(unsigned u) {
    return __uint_as_float(u << 16);
}
__device__ __forceinline__ float ubf_hi(unsigned u) {
    return __uint_as_float(u & 0xffff0000u);
}

// ---------------------------------------------------------------------------
// Prep: Wt[col][k] = bf16(W[k][col]), stored as uint (2 bf16, k-pairs packed).
// 32 KB output, L1/L2-resident for the GEMM. 8192 threads, one uint each.
// ---------------------------------------------------------------------------
__global__ __launch_bounds__(256) void prep_wt(const float* __restrict__ w,
                                               unsigned* __restrict__ wtu) {
    const int i   = blockIdx.x * 256 + threadIdx.x;   // 0..8191
    const int col = i >> 6;                            // 0..127
    const int k2  = i & 63;                            // 0..63 (pair index)
    const float a = w[(size_t)(2 * k2) * D + col];
    const float b = w[(size_t)(2 * k2 + 1) * D + col];
    wtu[i] = pack_bf16(a, b);
}

// ---------------------------------------------------------------------------
// Kernel 1: h = x @ W via bf16 MFMA (16x16x32). One wave = 16 output rows.
// A-frag: lane holds x[r0 + (lane&15)][kc*32 + (lane>>4)*8 .. +7], converted
// fp32->bf16 in flight. B-frag: Wt[col][same k slice] (contiguous via prep).
// Both frags use the same k-slot mapping -> dot product is exact over k.
// C/D layout (verified m89): col = lane&15, row = (lane>>4)*4 + reg.
// h written as bf16 (ushort); quarter-wave stores are 32B-contiguous.
// ---------------------------------------------------------------------------
__global__ __launch_bounds__(256) void gemm_mfma(const float4* __restrict__ x4,
                                                 const uint4* __restrict__ wt4,
                                                 ushort* __restrict__ hb) {
    const int lane = threadIdx.x & 63;
    const int r0   = blockIdx.x * 64 + (threadIdx.x >> 6) * 16;  // wave row base
    const int arow = r0 + (lane & 15);
    const int kg   = lane >> 4;                  // k-group 0..3
    const bool rok = (arow < N_NODES);

    // A fragments: 4 K-chunks of 32; per chunk 8 bf16 from 2 float4 loads.
    bf16x8 afr[4];
    #pragma unroll
    for (int kc = 0; kc < 4; ++kc) {
        float4 f0 = make_float4(0.f, 0.f, 0.f, 0.f);
        float4 f1 = f0;
        if (rok) {
            const int c4 = kc * 8 + kg * 2;      // float4 index within row
            f0 = x4[(size_t)arow * D4 + c4];
            f1 = x4[(size_t)arow * D4 + c4 + 1];
        }
        union { bf16x8 v; unsigned u[4]; } a;
        a.u[0] = pack_bf16(f0.x, f0.y);
        a.u[1] = pack_bf16(f0.z, f0.w);
        a.u[2] = pack_bf16(f1.x, f1.y);
        a.u[3] = pack_bf16(f1.z, f1.w);
        afr[kc] = a.v;
    }

    // 8 column tiles x 4 K-chunks of MFMA.
    f32x4 acc[8];
    #pragma unroll
    for (int t = 0; t < 8; ++t) acc[t] = (f32x4){0.f, 0.f, 0.f, 0.f};

    #pragma unroll
    for (int t = 0; t < 8; ++t) {
        const int col = t * 16 + (lane & 15);
        #pragma unroll
        for (int kc = 0; kc < 4; ++kc) {
            union { bf16x8 v; uint4 u; } b;
            b.u = wt4[(size_t)col * 16 + kc * 4 + kg];   // Wt row: 16 uint4
            acc[t] = __builtin_amdgcn_mfma_f32_16x16x32_bf16(afr[kc], b.v,
                                                             acc[t], 0, 0, 0);
        }
    }

    // Store bf16 h. Lane writes col (lane&15 + t*16), rows r0+(lane>>4)*4+j.
    #pragma unroll
    for (int t = 0; t < 8; ++t) {
        const int col = t * 16 + (lane & 15);
        #pragma unroll
        for (int j = 0; j < 4; ++j) {
            const int r = r0 + (lane >> 4) * 4 + j;
            if (r < N_NODES)
                hb[(size_t)r * D + col] = (ushort)bf16_1(acc[t][j]);
        }
    }
}

// ---------------------------------------------------------------------------
// Zero the per-row counter array (replaces hipMemsetAsync dispatch).
// ---------------------------------------------------------------------------
__global__ __launch_bounds__(256) void zero_cnt(int4* __restrict__ cnt4) {
    const int i = blockIdx.x * 256 + threadIdx.x;
    if (i < (N_NODES + 3) / 4) cnt4[i] = make_int4(0, 0, 0, 0);
}

// ---------------------------------------------------------------------------
// CSR step A: count edges per row AND hand each edge its within-row ticket.
// ---------------------------------------------------------------------------
__global__ __launch_bounds__(256) void count_tickets(const int* __restrict__ rowi,
                                                     int* __restrict__ cnt,
                                                     int* __restrict__ pos) {
    const int e = blockIdx.x * 256 + threadIdx.x;
    if (e < N_EDGES) pos[e] = atomicAdd(&cnt[rowi[e]], 1);
}

// ---------------------------------------------------------------------------
// CSR step B1: per-block sums of cnt (196 blocks x 256).
// ---------------------------------------------------------------------------
__global__ __launch_bounds__(SCAN_B) void scan_phase1(const int* __restrict__ cnt,
                                                      int* __restrict__ partials) {
    __shared__ int red[SCAN_B / 64];
    const int t = threadIdx.x;
    const int i = blockIdx.x * SCAN_B + t;
    int v = (i < N_NODES) ? cnt[i] : 0;
    #pragma unroll
    for (int off = 32; off > 0; off >>= 1) v += __shfl_down(v, off);
    if ((t & 63) == 0) red[t >> 6] = v;
    __syncthreads();
    if (t == 0) partials[blockIdx.x] = red[0] + red[1] + red[2] + red[3];
}

// ---------------------------------------------------------------------------
// CSR step B2: exclusive scan of the 196 partials (single tiny block).
// ---------------------------------------------------------------------------
__global__ __launch_bounds__(SCAN_B) void scan_phase2(int* __restrict__ partials) {
    __shared__ int s[SCAN_B];
    const int t = threadIdx.x;
    int v = (t < SCAN_NB) ? partials[t] : 0;
    s[t] = v;
    __syncthreads();
    #pragma unroll
    for (int off = 1; off < SCAN_B; off <<= 1) {
        int u = (t >= off) ? s[t - off] : 0;
        __syncthreads();
        s[t] += u;
        __syncthreads();
    }
    if (t < SCAN_NB) partials[t] = (t == 0) ? 0 : s[t - 1];   // exclusive
}

// ---------------------------------------------------------------------------
// CSR step B3: per-block exclusive scan + block offset -> starts[].
// ---------------------------------------------------------------------------
__global__ __launch_bounds__(SCAN_B) void scan_phase3(const int* __restrict__ cnt,
                                                      const int* __restrict__ partials,
                                                      int* __restrict__ starts) {
    __shared__ int s[SCAN_B];
    const int t = threadIdx.x;
    const int i = blockIdx.x * SCAN_B + t;
    int v = (i < N_NODES) ? cnt[i] : 0;
    s[t] = v;
    __syncthreads();
    #pragma unroll
    for (int off = 1; off < SCAN_B; off <<= 1) {
        int u = (t >= off) ? s[t - off] : 0;
        __syncthreads();
        s[t] += u;
        __syncthreads();
    }
    if (i < N_NODES)
        starts[i] = partials[blockIdx.x] + ((t == 0) ? 0 : s[t - 1]);
    if (i == 0) starts[N_NODES] = N_EDGES;  // total is a compile-time constant
}

// ---------------------------------------------------------------------------
// CSR step C: place each edge's packed (col:16 | bf16(val):16) word at
// starts[row] + ticket. No atomics; 4 B random write per edge.
// ---------------------------------------------------------------------------
__global__ __launch_bounds__(256) void place_edges(const int* __restrict__ rowi,
                                                   const int* __restrict__ coli,
                                                   const float* __restrict__ vals,
                                                   const int* __restrict__ pos,
                                                   const int* __restrict__ starts,
                                                   unsigned* __restrict__ perm) {
    const int e = blockIdx.x * 256 + threadIdx.x;
    if (e >= N_EDGES) return;
    const int p = starts[rowi[e]] + pos[e];
    perm[p] = ((unsigned)coli[e] << 16) | bf16_1(vals[e]);
}

// ---------------------------------------------------------------------------
// Kernel 2: gather. One 64-lane wave per node; lane owns 2 features (one
// packed-bf16 uint of h). 8 edges unrolled -> 8 row-gathers in flight; tail
// loads clamp to the last real edge (L1 hit) with zeroed weight.
// Fused bias + ReLU on the single fp32 output write. No atomics.
// ---------------------------------------------------------------------------
__global__ __launch_bounds__(256) void gather_nodes(const int* __restrict__ starts,
                                                    const unsigned* __restrict__ perm,
                                                    const unsigned* __restrict__ hb,
                                                    const float2* __restrict__ bias2,
                                                    float2* __restrict__ out2) {
    const int node = blockIdx.x * 4 + (threadIdx.x >> 6);
    const int lane = threadIdx.x & 63;
    if (node >= N_NODES) return;

    const int s = __builtin_amdgcn_readfirstlane(starts[node]);
    const int e = __builtin_amdgcn_readfirstlane(starts[node + 1]);

    float2 acc = {0.f, 0.f};
    for (int j0 = s; j0 < e; j0 += 8) {
        unsigned hv[8];
        float    vv[8];
        #pragma unroll
        for (int q = 0; q < 8; ++q) {
            const int jq = j0 + q;
            const int jj = (jq < e) ? jq : (e - 1);          // clamp -> L1 hit
            const unsigned ed = __builtin_amdgcn_readfirstlane(perm[jj]);
            const int c = (int)(ed >> 16);
            vv[q] = (jq < e) ? __uint_as_float((ed & 0xffffu) << 16) : 0.f;
            hv[q] = hb[(size_t)c * 64 + lane];               // 256B/edge, coalesced
        }
        #pragma unroll
        for (int q = 0; q < 8; ++q) {
            acc.x = fmaf(vv[q], ubf_lo(hv[q]), acc.x);
            acc.y = fmaf(vv[q], ubf_hi(hv[q]), acc.y);
        }
    }
    const float2 b = bias2[lane];
    out2[(size_t)node * D2 + lane] =
        make_float2(fmaxf(acc.x + b.x, 0.f), fmaxf(acc.y + b.y, 0.f));
}

extern "C" void kernel_launch(void* const* d_in, const int* in_sizes, int n_in,
                              void* d_out, int out_size, void* d_ws, size_t ws_size,
                              hipStream_t stream) {
    const float* x      = (const float*)d_in[0];   // [N_NODES, D]
    const float* weight = (const float*)d_in[1];   // [D, D]
    const float* bias   = (const float*)d_in[2];   // [D]
    const float* vals   = (const float*)d_in[3];   // [N_EDGES]
    const int*   rowi   = (const int*)d_in[4];     // [N_EDGES]
    const int*   coli   = (const int*)d_in[5];     // [N_EDGES]
    float* out = (float*)d_out;                    // [N_NODES, D]

    // Workspace layout (16B-aligned):
    //   hb       : N_NODES*128 ushorts (bf16 h) = 12.8 MB
    //   starts   : N_NODES+1 ints   ~ 200 KB
    //   cnt      : N_NODES ints     = 200 KB
    //   pos      : N_EDGES ints     = 3.2 MB  (tickets)
    //   partials : 256 ints
    //   wt       : 128*64 uints (bf16 W^T) = 32 KB
    //   perm     : N_EDGES uints    = 3.2 MB  (packed col|bf16 val)
    char* w = (char*)d_ws;
    ushort* hb       = (ushort*)w;    w += (size_t)N_NODES * D * sizeof(ushort);
    int*   starts    = (int*)w;       w += ((size_t)N_NODES + 16) * sizeof(int);
    int*   cnt       = (int*)w;       w += ((size_t)N_NODES + 16) * sizeof(int);
    int*   pos       = (int*)w;       w += (size_t)N_EDGES * sizeof(int);
    int*   partials  = (int*)w;       w += 256 * sizeof(int);
    unsigned* wt     = (unsigned*)w;  w += (size_t)D * 64 * sizeof(unsigned);
    unsigned* perm   = (unsigned*)w;

    // --- CSR build (ticketed, single atomic pass) ---
    zero_cnt<<<(N_NODES / 4 + 255) / 256, 256, 0, stream>>>((int4*)cnt);
    count_tickets<<<N_EDGES / 256, 256, 0, stream>>>(rowi, cnt, pos);
    scan_phase1<<<SCAN_NB, SCAN_B, 0, stream>>>(cnt, partials);
    scan_phase2<<<1, SCAN_B, 0, stream>>>(partials);
    scan_phase3<<<SCAN_NB, SCAN_B, 0, stream>>>(cnt, partials, starts);
    place_edges<<<N_EDGES / 256, 256, 0, stream>>>(rowi, coli, vals, pos, starts, perm);

    // --- h = x @ W via bf16 MFMA ---
    prep_wt<<<32, 256, 0, stream>>>(weight, wt);
    gemm_mfma<<<(N_NODES + 63) / 64, 256, 0, stream>>>((const float4*)x,
                                                       (const uint4*)wt, hb);

    // --- out[i] = relu(sum_e vals[e]*h[col[e]] + bias), no atomics ---
    gather_nodes<<<(N_NODES + 3) / 4, 256, 0, stream>>>(starts, perm,
                                                        (const unsigned*)hb,
                                                        (const float2*)bias,
                                                        (float2*)out);
}